// Round 1
// baseline (1690.600 us; speedup 1.0000x reference)
//
#include <hip/hip_runtime.h>

typedef __attribute__((ext_vector_type(8))) short s16x8;
typedef __attribute__((ext_vector_type(4))) float f32x4;
typedef __attribute__((ext_vector_type(4))) unsigned short u16x4;

#define MFMA16(a, b, c) __builtin_amdgcn_mfma_f32_16x16x32_bf16((a), (b), (c), 0, 0, 0)

static __device__ __forceinline__ unsigned short fbf(float x) {
  unsigned int u = __builtin_bit_cast(unsigned int, x);
  u += 0x7fffu + ((u >> 16) & 1u);
  return (unsigned short)(u >> 16);
}

// ---------------- prep: convert weights to bf16, gather rel-pos bias table ----------------
// work items: [0,196608) qkv_w -> bf16 ; [196608,262144) proj_w -> bf16 ;
//             [262144,294912) bias_tab[h][n][m] = rel_table[relidx(n,m)][h]
__global__ void __launch_bounds__(256) prep_kernel(
    const float* __restrict__ qkv_w, const float* __restrict__ proj_w,
    const float* __restrict__ rel_table,
    unsigned short* __restrict__ wqkv, unsigned short* __restrict__ wproj,
    float* __restrict__ btab) {
  int i = blockIdx.x * 256 + threadIdx.x;
  if (i < 196608) {
    wqkv[i] = fbf(qkv_w[i]);
  } else if (i < 262144) {
    int j = i - 196608;
    wproj[j] = fbf(proj_w[j]);
  } else {
    int j = i - 262144;                 // [0, 32768)
    int h = j >> 12, nm = j & 4095;
    int n = nm >> 6, m = nm & 63;
    int rid = ((n >> 3) - (m >> 3) + 7) * 15 + ((n & 7) - (m & 7) + 7);
    btab[h * 4096 + nm] = rel_table[rid * 8 + h];
  }
}

// ---------------- fused window-MSA kernel: 1 block = 1 window ----------------
// LDS map (bytes):
//   [0, 32768)            xs : x window bf16 [64][256], XOR-swizzled (byte ^= (row&7)<<4)
//                              reused after phase2 as attn-out bf16 [64][256] (same swizzle)
//   per wave w at waveBase = 32768 + w*29696 :
//     H(hl) = waveBase + hl*10240 :  q [64][40 bf16] (5120 B) | k [64][40 bf16] (5120 B)
//                                     -> overwritten by P [64][72 bf16] after S-MFMAs
//     vt    = waveBase + 20480 + hl*4608 : v^T [32][72 bf16]
//     phase4: fp32 out slice [64][68] (17408 B) overlays H(0)+H(1)
__global__ void __launch_bounds__(256, 1) wmsa_kernel(
    const float* __restrict__ x, const float* __restrict__ mask,
    const float* __restrict__ qkv_b, const float* __restrict__ proj_b,
    const unsigned short* __restrict__ wqkv, const unsigned short* __restrict__ wproj,
    const float* __restrict__ btab, float* __restrict__ out) {
  __shared__ __align__(16) char sm[151552];
  const int tid = threadIdx.x;
  const int w = tid >> 6;          // wave id 0..3 (owns heads 2w, 2w+1)
  const int lid = tid & 63;
  const int g = lid >> 4;          // 16-lane group 0..3
  const int c = lid & 15;          // lane-in-group
  const int win = blockIdx.x;
  const long xbase = (long)win * 16384;

  const int waveBase = 32768 + w * 29696;
  const int vtoff = waveBase + 20480;
  const int swz = (c & 7) << 4;    // row&7 == c&7 for rows of form mt*16+c

  // ---- phase 1: stage x window -> bf16 LDS (swizzled) ----
#pragma unroll
  for (int i = 0; i < 16; ++i) {
    int t2 = i * 256 + tid;
    int row = t2 >> 6;
    int c4 = (t2 & 63) * 4;
    float4 v = *(const float4*)(x + xbase + row * 256 + c4);
    u16x4 hv = { fbf(v.x), fbf(v.y), fbf(v.z), fbf(v.w) };
    int byte = ((row << 9) + (c4 << 1)) ^ ((row & 7) << 4);
    *(u16x4*)(sm + byte) = hv;
  }
  __syncthreads();

  // ---- phase 2: QKV GEMM for this wave's 2 heads ----
  s16x8 af[4][8];
#pragma unroll
  for (int mt = 0; mt < 4; ++mt)
#pragma unroll
    for (int kk = 0; kk < 8; ++kk) {
      int row = mt * 16 + c;
      int byte = ((row << 9) + ((kk * 32 + g * 8) << 1)) ^ swz;
      af[mt][kk] = *(const s16x8*)(sm + byte);
    }

  const f32x4 fzero = {0.f, 0.f, 0.f, 0.f};
#pragma unroll
  for (int j = 0; j < 6; ++j) {
    const int gq = j >> 1;          // 0=Q 1=K 2=V
    const int half = j & 1;         // which of the wave's two heads
    const int cb = gq * 256 + w * 64 + half * 32;
    f32x4 acc2[2][4];
#pragma unroll
    for (int nt = 0; nt < 2; ++nt)
#pragma unroll
      for (int mt = 0; mt < 4; ++mt) acc2[nt][mt] = fzero;

#pragma unroll
    for (int kk = 0; kk < 8; ++kk) {
      s16x8 b0 = *(const s16x8*)(wqkv + ((cb + c) << 8) + kk * 32 + g * 8);
      s16x8 b1 = *(const s16x8*)(wqkv + ((cb + 16 + c) << 8) + kk * 32 + g * 8);
#pragma unroll
      for (int mt = 0; mt < 4; ++mt) {
        acc2[0][mt] = MFMA16(af[mt][kk], b0, acc2[0][mt]);
        acc2[1][mt] = MFMA16(af[mt][kk], b1, acc2[1][mt]);
      }
    }
#pragma unroll
    for (int nt = 0; nt < 2; ++nt) {
      int col = cb + nt * 16 + c;
      float bb = qkv_b[col];
      int dim = nt * 16 + c;
#pragma unroll
      for (int mt = 0; mt < 4; ++mt) {
#pragma unroll
        for (int jj = 0; jj < 4; ++jj) {
          int row = mt * 16 + g * 4 + jj;
          float v = acc2[nt][mt][jj] + bb;
          int addr;
          if (gq == 0) {
            v *= 0.17677669529663687f;  // 1/sqrt(32)
            addr = waveBase + half * 10240 + row * 80 + dim * 2;
          } else if (gq == 1) {
            addr = waveBase + half * 10240 + 5120 + row * 80 + dim * 2;
          } else {
            addr = vtoff + half * 4608 + dim * 144 + row * 2;  // transposed V
          }
          *(unsigned short*)(sm + addr) = fbf(v);
        }
      }
    }
  }
  __syncthreads();   // xs dead -> reusable as attn-out

  // ---- phase 3: attention, per head (wave-local) ----
#pragma unroll
  for (int hl = 0; hl < 2; ++hl) {
    const int Hb = waveBase + hl * 10240;
    s16x8 aq[4], bk[4];
#pragma unroll
    for (int mt = 0; mt < 4; ++mt)
      aq[mt] = *(const s16x8*)(sm + Hb + (mt * 16 + c) * 80 + g * 16);
#pragma unroll
    for (int nt = 0; nt < 4; ++nt)
      bk[nt] = *(const s16x8*)(sm + Hb + 5120 + (nt * 16 + c) * 80 + g * 16);

    f32x4 sacc[4][4];
#pragma unroll
    for (int mt = 0; mt < 4; ++mt)
#pragma unroll
      for (int nt = 0; nt < 4; ++nt) sacc[mt][nt] = MFMA16(aq[mt], bk[nt], fzero);

    const float* bp = btab + (2 * w + hl) * 4096;
    const float* mp = mask + (long)(win & 4095) * 4096;
    float rinv[4][4];
#pragma unroll
    for (int mt = 0; mt < 4; ++mt) {
#pragma unroll
      for (int jj = 0; jj < 4; ++jj) {
        int rb = (mt * 16 + g * 4 + jj) * 64 + c;
        float s0 = sacc[mt][0][jj] + bp[rb] + mp[rb];
        float s1 = sacc[mt][1][jj] + bp[rb + 16] + mp[rb + 16];
        float s2 = sacc[mt][2][jj] + bp[rb + 32] + mp[rb + 32];
        float s3 = sacc[mt][3][jj] + bp[rb + 48] + mp[rb + 48];
        float mx = fmaxf(fmaxf(s0, s1), fmaxf(s2, s3));
        mx = fmaxf(mx, __shfl_xor(mx, 1));
        mx = fmaxf(mx, __shfl_xor(mx, 2));
        mx = fmaxf(mx, __shfl_xor(mx, 4));
        mx = fmaxf(mx, __shfl_xor(mx, 8));
        float p0 = __expf(s0 - mx), p1 = __expf(s1 - mx);
        float p2 = __expf(s2 - mx), p3 = __expf(s3 - mx);
        float sum = p0 + p1 + p2 + p3;
        sum += __shfl_xor(sum, 1);
        sum += __shfl_xor(sum, 2);
        sum += __shfl_xor(sum, 4);
        sum += __shfl_xor(sum, 8);
        rinv[mt][jj] = 1.0f / sum;
        sacc[mt][0][jj] = p0; sacc[mt][1][jj] = p1;
        sacc[mt][2][jj] = p2; sacc[mt][3][jj] = p3;
      }
    }
    // write P (bf16, stride 72) over dead q/k block of this head
#pragma unroll
    for (int mt = 0; mt < 4; ++mt)
#pragma unroll
      for (int nt = 0; nt < 4; ++nt)
#pragma unroll
        for (int jj = 0; jj < 4; ++jj) {
          int row = mt * 16 + g * 4 + jj;
          *(unsigned short*)(sm + Hb + row * 144 + (nt * 16 + c) * 2) =
              fbf(sacc[mt][nt][jj]);
        }
    // PV
    f32x4 vacc[4][2];
#pragma unroll
    for (int mt = 0; mt < 4; ++mt) { vacc[mt][0] = fzero; vacc[mt][1] = fzero; }
#pragma unroll
    for (int kkp = 0; kkp < 2; ++kkp) {
      s16x8 bv0 = *(const s16x8*)(sm + vtoff + hl * 4608 + c * 144 + kkp * 64 + g * 16);
      s16x8 bv1 = *(const s16x8*)(sm + vtoff + hl * 4608 + (16 + c) * 144 + kkp * 64 + g * 16);
#pragma unroll
      for (int mt = 0; mt < 4; ++mt) {
        s16x8 ap = *(const s16x8*)(sm + Hb + (mt * 16 + c) * 144 + kkp * 64 + g * 16);
        vacc[mt][0] = MFMA16(ap, bv0, vacc[mt][0]);
        vacc[mt][1] = MFMA16(ap, bv1, vacc[mt][1]);
      }
    }
    // attn-out -> swizzled bf16 buffer at LDS offset 0
#pragma unroll
    for (int mt = 0; mt < 4; ++mt)
#pragma unroll
      for (int nt = 0; nt < 2; ++nt)
#pragma unroll
        for (int jj = 0; jj < 4; ++jj) {
          int row = mt * 16 + g * 4 + jj;
          int colg = (2 * w + hl) * 32 + nt * 16 + c;
          int byte = ((row << 9) + (colg << 1)) ^ ((row & 7) << 4);
          *(unsigned short*)(sm + byte) = fbf(vacc[mt][nt][jj] * rinv[mt][jj]);
        }
  }
  __syncthreads();   // all waves' attn-out columns visible

  // ---- phase 4: output projection ----
#pragma unroll
  for (int mt = 0; mt < 4; ++mt)
#pragma unroll
    for (int kk = 0; kk < 8; ++kk) {
      int row = mt * 16 + c;
      int byte = ((row << 9) + ((kk * 32 + g * 8) << 1)) ^ swz;
      af[mt][kk] = *(const s16x8*)(sm + byte);
    }
#pragma unroll
  for (int nt = 0; nt < 4; ++nt) {
    f32x4 pacc[4];
#pragma unroll
    for (int mt = 0; mt < 4; ++mt) pacc[mt] = fzero;
#pragma unroll
    for (int kk = 0; kk < 8; ++kk) {
      s16x8 bw = *(const s16x8*)(wproj + ((w * 64 + nt * 16 + c) << 8) + kk * 32 + g * 8);
#pragma unroll
      for (int mt = 0; mt < 4; ++mt) pacc[mt] = MFMA16(af[mt][kk], bw, pacc[mt]);
    }
    int col = w * 64 + nt * 16 + c;
    float bb = proj_b[col];
#pragma unroll
    for (int mt = 0; mt < 4; ++mt)
#pragma unroll
      for (int jj = 0; jj < 4; ++jj) {
        int row = mt * 16 + g * 4 + jj;
        *(float*)(sm + waveBase + (row * 68 + nt * 16 + c) * 4) = pacc[mt][jj] + bb;
      }
  }
  // coalesced float4 store of this wave's 64x64 fp32 slice
#pragma unroll
  for (int it = 0; it < 16; ++it) {
    int row = it * 4 + g;
    float4 vv = *(const float4*)(sm + waveBase + row * 272 + c * 16);
    *(float4*)(out + xbase + row * 256 + w * 64 + c * 4) = vv;
  }
}

extern "C" void kernel_launch(void* const* d_in, const int* in_sizes, int n_in,
                              void* d_out, int out_size, void* d_ws, size_t ws_size,
                              hipStream_t stream) {
  const float* x = (const float*)d_in[0];
  const float* attn_mask = (const float*)d_in[1];
  const float* qkv_w = (const float*)d_in[2];
  const float* qkv_b = (const float*)d_in[3];
  const float* rel_table = (const float*)d_in[4];
  const float* proj_w = (const float*)d_in[5];
  const float* proj_b = (const float*)d_in[6];

  unsigned short* wqkv = (unsigned short*)d_ws;                       // 768*256 bf16
  unsigned short* wproj = wqkv + 196608;                              // 256*256 bf16
  float* btab = (float*)((char*)d_ws + 524288);                       // [8][64][64] f32

  prep_kernel<<<1152, 256, 0, stream>>>(qkv_w, proj_w, rel_table, wqkv, wproj, btab);
  wmsa_kernel<<<8192, 256, 0, stream>>>(x, attn_mask, qkv_b, proj_b,
                                        wqkv, wproj, btab, (float*)d_out);
}